// Round 5
// baseline (57.388 us; speedup 1.0000x reference)
//
#include <hip/hip_runtime.h>

// Problem constants (fixed by setup_inputs)
#define B 16
#define L 1024
#define D 512
#define T 8192            // mel_max_length
#define D4 (D / 4)        // 128 float4 per row
#define NA (B * L / 2)    // 8192 token-pair blocks (2 tokens each)
#define NB (B * T / 16)   // 8192 fill blocks (16 rows each)

typedef float f4 __attribute__((ext_vector_type(4)));
typedef int   i4 __attribute__((ext_vector_type(4)));

// One fused kernel, two block roles, no workspace.
//  - Token blocks (bid < NA): tokens l0=2q, l0+1 of batch b. Recompute
//    prefix = sum(dur[0..l0)) via int4 load + block reduce, then scatter the
//    two x rows into out rows [s0, s0+d0+d1) with nt stores.
//  - Fill blocks: rows [16q, 16q+16) of batch b; write zeros where t >= total.
// All blocks of batch pair (2k,2k+1) land on XCD k (chunked swizzle), so each
// XCD's L2 only ever holds its two 4 KB dur rows; x/out streams bypass via nt.
__global__ __launch_bounds__(256) void lr_fused(const float* __restrict__ x,
                                                const int* __restrict__ dur,
                                                float* __restrict__ out) {
    const int tid     = threadIdx.x;
    const int wid     = tid >> 6;
    const int sub     = tid >> 7;        // 0/1: which row of a pair
    const int lane128 = tid & 127;       // float4 column within a row

    __shared__ int ws4[4];
    __shared__ int bc[2];

    const int  bid = blockIdx.x;
    const bool isA = bid < NA;
    int rel = isA ? bid : bid - NA;
    rel = ((rel & 7) << 10) + (rel >> 3);   // 8192-range XCD-chunked swizzle

    const int b = rel >> 9;              // batch
    const int q = rel & 511;             // pair index (A) / row-group (B)

    // ---- shared front: load dur row (4 KB, L2-hot) and reduce a prefix ----
    const int limit = isA ? (q << 1) : L;          // sum of dur[j], j < limit
    const i4  dv    = reinterpret_cast<const i4*>(dur + b * L)[tid];

    int part = 0;
    #pragma unroll
    for (int e = 0; e < 4; ++e)
        part += ((tid << 2) + e < limit) ? dv[e] : 0;

    if (isA && tid == (limit >> 2)) {              // owner of dur[l0], dur[l0+1]
        bc[0] = dv[limit & 3];
        bc[1] = dv[(limit & 3) + 1];               // l0 even -> stays in int4
    }

    #pragma unroll
    for (int off = 32; off > 0; off >>= 1)
        part += __shfl_xor(part, off, 64);
    if ((tid & 63) == 0) ws4[wid] = part;
    __syncthreads();
    const int s0 = ws4[0] + ws4[1] + ws4[2] + ws4[3];

    f4* __restrict__ ob = reinterpret_cast<f4*>(out) + (size_t)b * T * D4;

    if (isA) {
        const int d0 = bc[0], d1 = bc[1];
        const int e0 = s0 + d0, e1 = e0 + d1;
        if (e1 == s0) return;                      // both tokens empty

        const f4* __restrict__ xr =
            reinterpret_cast<const f4*>(x) + ((size_t)b * L + (q << 1)) * D4;
        const f4 v0 = __builtin_nontemporal_load(xr + lane128);
        const f4 v1 = __builtin_nontemporal_load(xr + D4 + lane128);

        for (int r = s0 + sub; r < e1; r += 2) {
            const f4 v = (r < e0) ? v0 : v1;
            __builtin_nontemporal_store(v, &ob[(size_t)r * D4 + lane128]);
        }
    } else {
        const int total = s0;
        const int t0    = q << 4;
        if (t0 + 16 <= total) return;              // fully valid row-group

        const f4 z = (f4)(0.f);
        #pragma unroll
        for (int it = 0; it < 8; ++it) {
            const int t = t0 + (it << 1) + sub;
            if (t >= total)
                __builtin_nontemporal_store(z, &ob[(size_t)t * D4 + lane128]);
        }
    }
}

extern "C" void kernel_launch(void* const* d_in, const int* in_sizes, int n_in,
                              void* d_out, int out_size, void* d_ws, size_t ws_size,
                              hipStream_t stream) {
    const float* x   = (const float*)d_in[0];
    const int*   dur = (const int*)d_in[1];
    float*       out = (float*)d_out;

    lr_fused<<<NA + NB, 256, 0, stream>>>(x, dur, out);
}